// Round 1
// baseline (6365.385 us; speedup 1.0000x reference)
//
#include <hip/hip_runtime.h>
#include <hip/hip_bf16.h>
#include <math.h>

// RITS-style RNN + late attention, fused persistent kernel. Round 4:
//  - Phase 7 (scores = s1 @ Ws2^T) moved from a 350-deep serial fmaf chain with
//    175 global float2 loads/thread (120 threads) onto MFMA: s1 stored as bf16
//    in sh_s1b[16][392] (same 784B row stride as sh_ab -> 2-way bank alias,
//    free), Ws2 pre-swizzled into B-fragments (b7: 2 n-tiles x 11 k-tiles).
//  - x/d/m (+msum) prefetched into registers one step ahead: HBM/L3 latency
//    hides under phases 2..8 instead of stalling barrier S1.
//  - Per-step global bias loads (td_h_b/hist_b/Ws1_b/Ws2_b) hoisted to
//    registers before the t-loop.
//  - Phase 5 ntl unroll 2 -> 4 (more frag loads in flight vs ~400cy L2 lat).
// ws layout: f32 ws[0]=xl ws[1]=y ws[2]=tr_sum ws[16..272)=msum; then bf16
// B-frag tensors at WS_B5/B6/B3/B2/B7 (total ~1.03 MB).

#define BB 1024
#define SS 256
#define NF 64
#define HD 256
#define DAA 350
#define DRR 30

#define WS_B5_OFS 4096
#define WS_B5_ELEMS (64 * 12 * 64 * 8)   // gates: 64 n-tiles x 12 k-tiles
#define WS_B6_OFS (WS_B5_OFS + WS_B5_ELEMS * 2)
#define WS_B6_ELEMS (22 * 8 * 64 * 8)    // Ws1: 22 n-tiles x 8 k-tiles
#define WS_B3_OFS (WS_B6_OFS + WS_B6_ELEMS * 2)
#define WS_B3_ELEMS (4 * 8 * 64 * 8)     // hist: 4 n-tiles x 8 k-tiles
#define WS_B2_OFS (WS_B3_OFS + WS_B3_ELEMS * 2)
#define WS_B2_ELEMS (16 * 2 * 64 * 8)    // td_h: 16 n-tiles x 2 k-tiles
#define WS_B7_OFS (WS_B2_OFS + WS_B2_ELEMS * 2)
#define WS_B7_ELEMS (2 * 11 * 64 * 8)    // Ws2: 2 n-tiles x 11 k-tiles (K=350->352)
#define CW_TOTAL (WS_B5_ELEMS + WS_B6_ELEMS + WS_B3_ELEMS + WS_B2_ELEMS + WS_B7_ELEMS)

typedef __attribute__((ext_vector_type(8))) short bf16x8;
typedef __attribute__((ext_vector_type(4))) float f32x4;

__device__ __forceinline__ float dot4f(float4 a, float4 b) {
  return fmaf(a.x, b.x, fmaf(a.y, b.y, fmaf(a.z, b.z, a.w * b.w)));
}

__device__ __forceinline__ short f2bs(float v) {
  __hip_bfloat16 t = __float2bfloat16(v);
  return *reinterpret_cast<short*>(&t);
}

__global__ __launch_bounds__(256) void convert_weights(
    const float* __restrict__ W_ih, const float* __restrict__ W_hh,
    const float* __restrict__ Ws1_W, const float* __restrict__ hist_W,
    const float* __restrict__ td_h_W, const float* __restrict__ Ws2_W,
    short* __restrict__ b5, short* __restrict__ b6,
    short* __restrict__ b3, short* __restrict__ b2, short* __restrict__ b7)
{
  int idx = blockIdx.x * 256 + threadIdx.x;
  if (idx < WS_B5_ELEMS) {
    int j = idx & 7; int e8 = idx >> 3; int lane = e8 & 63; int tile = e8 >> 6;
    int kt = tile % 12, nt = tile / 12;
    int g = nt * 16 + (lane & 15);
    int k = kt * 32 + (lane >> 4) * 8 + j;  // [c_c(64)|m(64)|h(256)]
    float v = (k < 128) ? W_ih[g * 128 + k] : W_hh[g * 256 + (k - 128)];
    b5[idx] = f2bs(v);
  } else if (idx < WS_B5_ELEMS + WS_B6_ELEMS) {
    int i = idx - WS_B5_ELEMS;
    int j = i & 7; int e8 = i >> 3; int lane = e8 & 63; int tile = e8 >> 6;
    int kt = tile & 7, nt = tile >> 3;
    int a = nt * 16 + (lane & 15);
    int k = kt * 32 + (lane >> 4) * 8 + j;
    float v = (a < DAA) ? Ws1_W[a * 256 + k] : 0.f;
    b6[i] = f2bs(v);
  } else if (idx < WS_B5_ELEMS + WS_B6_ELEMS + WS_B3_ELEMS) {
    int i = idx - WS_B5_ELEMS - WS_B6_ELEMS;
    int j = i & 7; int e8 = i >> 3; int lane = e8 & 63; int tile = e8 >> 6;
    int kt = tile & 7, nt = tile >> 3;
    int n = nt * 16 + (lane & 15);
    int k = kt * 32 + (lane >> 4) * 8 + j;
    b3[i] = f2bs(hist_W[n * 256 + k]);
  } else if (idx < WS_B5_ELEMS + WS_B6_ELEMS + WS_B3_ELEMS + WS_B2_ELEMS) {
    int i = idx - WS_B5_ELEMS - WS_B6_ELEMS - WS_B3_ELEMS;
    int j = i & 7; int e8 = i >> 3; int lane = e8 & 63; int tile = e8 >> 6;
    int kt = tile & 1, nt = tile >> 1;
    int g = nt * 16 + (lane & 15);
    int k = kt * 32 + (lane >> 4) * 8 + j;
    b2[i] = f2bs(td_h_W[g * 64 + k]);
  } else if (idx < CW_TOTAL) {
    int i = idx - WS_B5_ELEMS - WS_B6_ELEMS - WS_B3_ELEMS - WS_B2_ELEMS;
    int j = i & 7; int e8 = i >> 3; int lane = e8 & 63; int tile = e8 >> 6;
    int kt = tile % 11, nt = tile / 11;
    int r = nt * 16 + (lane & 15);
    int k = kt * 32 + (lane >> 4) * 8 + j;
    float v = (r < DRR && k < DAA) ? Ws2_W[r * DAA + k] : 0.f;
    b7[i] = f2bs(v);
  }
}

__global__ __launch_bounds__(256) void prep_kernel(
    const float* __restrict__ masks, const float* __restrict__ is_train,
    float* __restrict__ ws)
{
  __shared__ float red[256];
  const int t = blockIdx.x;
  const int tid = threadIdx.x;
  float s = 0.f;
  for (int idx = tid; idx < BB * NF; idx += 256) {
    int b = idx >> 6, n = idx & 63;
    s += masks[(size_t)b * (SS * NF) + (size_t)t * NF + n];
  }
  red[tid] = s;
  __syncthreads();
  for (int off = 128; off > 0; off >>= 1) {
    if (tid < off) red[tid] += red[tid + off];
    __syncthreads();
  }
  if (tid == 0) ws[16 + t] = red[0] + 1e-5f;
  if (blockIdx.x == 0) {
    __syncthreads();
    float ts = 0.f;
    for (int idx = tid; idx < BB; idx += 256) ts += is_train[idx];
    red[tid] = ts;
    __syncthreads();
    for (int off = 128; off > 0; off >>= 1) {
      if (tid < off) red[tid] += red[tid + off];
      __syncthreads();
    }
    if (tid == 0) { ws[2] = red[0]; ws[0] = 0.f; ws[1] = 0.f; }
  }
}

__global__ __launch_bounds__(512, 2) void rits_main(
    const float* __restrict__ values, const float* __restrict__ masks_g,
    const float* __restrict__ deltas, const float* __restrict__ labels,
    const float* __restrict__ is_train,
    const float* __restrict__ td_h_b, const float* __restrict__ td_x_W,
    const float* __restrict__ td_x_b, const float* __restrict__ hist_b,
    const float* __restrict__ feat_W, const float* __restrict__ feat_b,
    const float* __restrict__ comb_W, const float* __restrict__ comb_b,
    const float* __restrict__ b_ih, const float* __restrict__ b_hh,
    const float* __restrict__ Ws1_b,
    const float* __restrict__ Ws2_W, const float* __restrict__ Ws2_b,
    const float* __restrict__ out_W, const float* __restrict__ out_b,
    float* __restrict__ out, float* __restrict__ ws)
{
  __shared__ __align__(16) float sh_a[4][384];   // f32: [unused|m|h]
  __shared__ __align__(16) short sh_ab[16][392]; // bf16 mirror [c_c|m|h], rows 4+ zero
  __shared__ __align__(16) short sh_db[16][72];  // bf16 d, rows 4+ zero
  __shared__ __align__(16) short sh_s1b[16][392];// bf16 s1 (tanh), rows 4+ zero
  __shared__ __align__(16) float sh_x[4][NF];
  __shared__ __align__(16) float sh_d[4][NF];
  __shared__ __align__(16) float sh_xc[4][NF];
  __shared__ __align__(16) float sh_gx[4][NF];
  __shared__ __align__(16) float sh_xh[4][NF];
  __shared__ __align__(16) float sh_gates[4][1024];
  __shared__ float sh_w[4][32];
  __shared__ float sh_scale[4][32];
  __shared__ float sh_M[4][32];
  __shared__ float sh_L[4][32];
  __shared__ float sh_msum;

  const int tid = threadIdx.x;
  const int b0 = blockIdx.x * 4;
  const int wv = tid >> 6;       // wave 0..7
  const int lane = tid & 63;
  const int lm = lane & 15;      // m/n within MFMA tile
  const int lq = lane >> 4;      // quad
  const int row = tid >> 7;      // LSTM/attention row
  const int j = tid & 127;
  const int jA = j, jB = j + 128;
  const int row2 = tid >> 6;     // feature-phase row (tid<256)
  const int nn = tid & 63;

  const bf16x8* b5 = (const bf16x8*)((const char*)ws + WS_B5_OFS);
  const bf16x8* b6 = (const bf16x8*)((const char*)ws + WS_B6_OFS);
  const bf16x8* b3 = (const bf16x8*)((const char*)ws + WS_B3_OFS);
  const bf16x8* b2 = (const bf16x8*)((const char*)ws + WS_B2_OFS);
  const bf16x8* b7 = (const bf16x8*)((const char*)ws + WS_B7_OFS);

  // ---- init LDS
  for (int i = tid; i < 16 * 392; i += 512) (&sh_ab[0][0])[i] = 0;
  for (int i = tid; i < 16 * 392; i += 512) (&sh_s1b[0][0])[i] = 0;
  for (int i = tid; i < 16 * 72; i += 512) (&sh_db[0][0])[i] = 0;
  for (int i = tid; i < 4 * 384; i += 512) (&sh_a[0][0])[i] = 0.f;
  if (tid < 128) {
    int rr = tid >> 5, q = tid & 31;
    sh_M[rr][q] = -1e30f;
    sh_L[rr][q] = 0.f;
  }

  // per-thread cached scalars
  const float tdxw  = td_x_W[nn * NF + nn];
  const float tdxb  = td_x_b[nn];
  const float featb = feat_b[nn];
  const float featd = feat_W[nn * NF + nn];
  const float combb = comb_b[nn];
  float bgA[4], bgB[4];
  #pragma unroll
  for (int q = 0; q < 4; ++q) {
    bgA[q] = b_ih[q * 256 + jA] + b_hh[q * 256 + jA];
    bgB[q] = b_ih[q * 256 + jB] + b_hh[q * 256 + jB];
  }

  // hoisted per-lane bias constants for the MFMA writer lanes (lq==0)
  float thb[2] = {0.f, 0.f};
  float hbv = 0.f;
  float w1b[3] = {0.f, 0.f, 0.f};
  float w2bv = 0.f;
  if (lq == 0) {
    thb[0] = td_h_b[(wv * 2 + 0) * 16 + lm];
    thb[1] = td_h_b[(wv * 2 + 1) * 16 + lm];
    if (wv < 4) hbv = hist_b[wv * 16 + lm];
    #pragma unroll
    for (int ii = 0; ii < 3; ++ii) {
      int a = (wv + 8 * ii) * 16 + lm;
      if (wv + 8 * ii < 22 && a < DAA) w1b[ii] = Ws1_b[a];
    }
    if (wv < 2) {
      int r = wv * 16 + lm;
      if (r < DRR) w2bv = Ws2_b[r];
    }
  }

  float cA = 0.f, cB = 0.f;
  float OA[DRR], OBv[DRR];
  #pragma unroll
  for (int r = 0; r < DRR; ++r) { OA[r] = 0.f; OBv[r] = 0.f; }
  double lossAcc = 0.0;

  // ---- prefetch t=0 inputs into registers
  float pv_a = 0.f, pv_b = 0.f, pv_msum = 0.f;
  if (tid < 256) {
    size_t g = (size_t)(b0 + row2) * (SS * NF) + nn;
    pv_a = values[g];
    pv_b = deltas[g];
  } else {
    int q = tid - 256; int rw = q >> 6, n2 = q & 63;
    size_t g = (size_t)(b0 + rw) * (SS * NF) + n2;
    pv_a = masks_g[g];
  }
  if (tid == 0) pv_msum = ws[16];

  __syncthreads();

  for (int t = 0; t < SS; ++t) {
    // ---- stage prefetched x,d (+bf16 d) on low half; m (f32+bf16) on high half
    if (tid < 256) {
      sh_x[row2][nn] = pv_a;
      sh_d[row2][nn] = pv_b;
      sh_db[row2][nn] = f2bs(pv_b);
    } else {
      int q = tid - 256;
      int rw = q >> 6, n2 = q & 63;
      sh_a[rw][64 + n2] = pv_a;
      sh_ab[rw][64 + n2] = f2bs(pv_a);
    }
    if (tid == 0) sh_msum = pv_msum;
    __syncthreads(); // S1

    // ---- issue next-step input loads; latency hides under phases 2..8
    if (t + 1 < SS) {
      if (tid < 256) {
        size_t g = (size_t)(b0 + row2) * (SS * NF) + (size_t)(t + 1) * NF + nn;
        pv_a = values[g];
        pv_b = deltas[g];
      } else {
        int q = tid - 256; int rw = q >> 6, n2 = q & 63;
        size_t g = (size_t)(b0 + rw) * (SS * NF) + (size_t)(t + 1) * NF + n2;
        pv_a = masks_g[g];
      }
      if (tid == 0) pv_msum = ws[16 + t + 1];
    }

    // ---- phase 2: gamma_h via MFMA (16 n-tiles over h); writers decay h.
    {
      bf16x8 dfr[2];
      #pragma unroll
      for (int kt = 0; kt < 2; ++kt)
        dfr[kt] = *(const bf16x8*)(&sh_db[lm][0] + kt * 32 + lq * 8);
      #pragma unroll
      for (int ntl = 0; ntl < 2; ++ntl) {
        int nt = wv * 2 + ntl;
        f32x4 acc = {0.f, 0.f, 0.f, 0.f};
        const bf16x8* bp = b2 + (size_t)(nt * 2) * 64 + lane;
        acc = __builtin_amdgcn_mfma_f32_16x16x32_bf16(dfr[0], bp[0], acc, 0, 0, 0);
        acc = __builtin_amdgcn_mfma_f32_16x16x32_bf16(dfr[1], bp[64], acc, 0, 0, 0);
        if (lq == 0) {
          int g = nt * 16 + lm;
          float bias = thb[ntl];
          #pragma unroll
          for (int r = 0; r < 4; ++r) {
            float gam = expf(-fmaxf(acc[r] + bias, 0.f));
            float h = sh_a[r][128 + g] * gam;
            sh_a[r][128 + g] = h;
            sh_ab[r][128 + g] = f2bs(h);
          }
        }
      }
      if (tid < 256) {
        float v = sh_d[row2][nn] * tdxw + tdxb;  // diag only
        sh_gx[row2][nn] = expf(-fmaxf(v, 0.f));
      }
    }
    __syncthreads(); // S2

    // ---- phase 3: x_h = h @ hist_W^T + b via MFMA (waves 0-3, 1 tile each)
    if (wv < 4) {
      int nt = wv;
      f32x4 acc = {0.f, 0.f, 0.f, 0.f};
      const bf16x8* bp = b3 + (size_t)(nt * 8) * 64 + lane;
      #pragma unroll
      for (int kt = 0; kt < 8; ++kt) {
        bf16x8 a = *(const bf16x8*)(&sh_ab[lm][128] + kt * 32 + lq * 8);
        acc = __builtin_amdgcn_mfma_f32_16x16x32_bf16(a, bp[kt * 64], acc, 0, 0, 0);
      }
      if (lq == 0) {
        int n = nt * 16 + lm;
        float bias = hbv;
        float lterm = 0.f;
        #pragma unroll
        for (int r = 0; r < 4; ++r) {
          float xh = acc[r] + bias;
          sh_xh[r][n] = xh;
          float m = sh_a[r][64 + n], x = sh_x[r][n];
          sh_xc[r][n] = m * x + (1.f - m) * xh;
          lterm += fabsf(x - xh) * m;
        }
        lossAcc += (double)(lterm / sh_msum);
      }
    }
    __syncthreads(); // S3

    // ---- phase 4: z_h (zero-diag feat), alpha, c_h, c_c (f32 VALU)
    if (tid < 256) {
      const float4* xc4 = (const float4*)&sh_xc[row2][0];
      const float4* gx4 = (const float4*)&sh_gx[row2][0];
      const float4* mm4 = (const float4*)&sh_a[row2][64];
      const float4* fW  = (const float4*)(feat_W + nn * NF);
      const float4* cW0 = (const float4*)(comb_W + nn * 2 * NF);
      const float4* cW1 = (const float4*)(comb_W + nn * 2 * NF + NF);
      float az = 0.f, aa = 0.f;
      #pragma unroll
      for (int k = 0; k < 16; ++k) {
        az += dot4f(xc4[k], fW[k]);
        aa += dot4f(gx4[k], cW0[k]);
        aa += dot4f(mm4[k], cW1[k]);
      }
      float xcn = sh_xc[row2][nn];
      float zh = az - xcn * featd + featb;
      float alpha = aa + combb;
      float xh = sh_xh[row2][nn];
      float chv = alpha * zh + (1.f - alpha) * xh;
      float m = sh_a[row2][64 + nn], x = sh_x[row2][nn];
      float ccv = m * x + (1.f - m) * chv;
      sh_ab[row2][nn] = f2bs(ccv);
      out[1 + BB + ((size_t)(b0 + row2) * SS + t) * NF + nn] = ccv;
      float lsum = (fabsf(x - zh) + fabsf(x - chv)) * m;
      lossAcc += (double)(lsum / sh_msum);
    }
    __syncthreads(); // S4

    // ---- phase 5: gates via MFMA. Wave wv owns n-tiles wv*8..wv*8+7.
    {
      bf16x8 afr[12];
      #pragma unroll
      for (int kt = 0; kt < 12; ++kt)
        afr[kt] = *(const bf16x8*)(&sh_ab[lm][0] + kt * 32 + lq * 8);
      #pragma unroll 4
      for (int ntl = 0; ntl < 8; ++ntl) {
        int nt = wv * 8 + ntl;
        f32x4 acc = {0.f, 0.f, 0.f, 0.f};
        const bf16x8* bp = b5 + (size_t)(nt * 12) * 64 + lane;
        #pragma unroll
        for (int kt = 0; kt < 12; ++kt)
          acc = __builtin_amdgcn_mfma_f32_16x16x32_bf16(afr[kt], bp[kt * 64], acc, 0, 0, 0);
        if (lq == 0) {
          int n = nt * 16 + lm;
          #pragma unroll
          for (int r = 0; r < 4; ++r) sh_gates[r][n] = acc[r];
        }
      }
    }
    __syncthreads(); // S5

    // ---- LSTM state update; write new h (f32 + bf16)
    float hnA, hnB;
    {
      float giA = sh_gates[row][jA] + bgA[0];
      float gfA = sh_gates[row][256 + jA] + bgA[1];
      float ggA = sh_gates[row][512 + jA] + bgA[2];
      float goA = sh_gates[row][768 + jA] + bgA[3];
      float iA = 1.f / (1.f + expf(-giA));
      float fA = 1.f / (1.f + expf(-gfA));
      float oA = 1.f / (1.f + expf(-goA));
      cA = fA * cA + iA * tanhf(ggA);
      hnA = oA * tanhf(cA);
      float giB = sh_gates[row][jB] + bgB[0];
      float gfB = sh_gates[row][256 + jB] + bgB[1];
      float ggB = sh_gates[row][512 + jB] + bgB[2];
      float goB = sh_gates[row][768 + jB] + bgB[3];
      float iB = 1.f / (1.f + expf(-giB));
      float fB = 1.f / (1.f + expf(-gfB));
      float oB = 1.f / (1.f + expf(-goB));
      cB = fB * cB + iB * tanhf(ggB);
      hnB = oB * tanhf(cB);
      sh_a[row][128 + jA] = hnA;
      sh_a[row][128 + jB] = hnB;
      sh_ab[row][128 + jA] = f2bs(hnA);
      sh_ab[row][128 + jB] = f2bs(hnB);
    }
    __syncthreads(); // S6

    // ---- phase 6: s1 = tanh(h @ Ws1^T + b1) via MFMA (22 tiles), bf16 out
    {
      bf16x8 hfr[8];
      #pragma unroll
      for (int kt = 0; kt < 8; ++kt)
        hfr[kt] = *(const bf16x8*)(&sh_ab[lm][128] + kt * 32 + lq * 8);
      #pragma unroll
      for (int ii = 0; ii < 3; ++ii) {
        int nt = wv + 8 * ii;
        if (nt < 22) {
          f32x4 acc = {0.f, 0.f, 0.f, 0.f};
          const bf16x8* bp = b6 + (size_t)(nt * 8) * 64 + lane;
          #pragma unroll
          for (int kt = 0; kt < 8; ++kt)
            acc = __builtin_amdgcn_mfma_f32_16x16x32_bf16(hfr[kt], bp[kt * 64], acc, 0, 0, 0);
          if (lq == 0) {
            int a = nt * 16 + lm;
            if (a < DAA) {
              float bias = w1b[ii];
              #pragma unroll
              for (int r = 0; r < 4; ++r)
                sh_s1b[r][a] = f2bs(tanhf(acc[r] + bias));
            }
          }
        }
      }
    }
    __syncthreads(); // S7

    // ---- phase 7: scores via MFMA (2 n-tiles x 11 k-tiles, waves 0-1) +
    //      online-softmax state (M, L, scale, w)
    if (wv < 2) {
      f32x4 acc = {0.f, 0.f, 0.f, 0.f};
      const bf16x8* bp = b7 + (size_t)(wv * 11) * 64 + lane;
      #pragma unroll
      for (int kt = 0; kt < 11; ++kt) {
        bf16x8 a = *(const bf16x8*)(&sh_s1b[lm][0] + kt * 32 + lq * 8);
        acc = __builtin_amdgcn_mfma_f32_16x16x32_bf16(a, bp[kt * 64], acc, 0, 0, 0);
      }
      if (lq == 0) {
        int r = wv * 16 + lm;
        if (r < DRR) {
          #pragma unroll
          for (int rr = 0; rr < 4; ++rr) {
            float sc = acc[rr] + w2bv;
            float Mo = sh_M[rr][r];
            float Mn = fmaxf(Mo, sc);
            float scl = expf(Mo - Mn);
            float w = expf(sc - Mn);
            sh_M[rr][r] = Mn;
            sh_L[rr][r] = sh_L[rr][r] * scl + w;
            sh_scale[rr][r] = scl;
            sh_w[rr][r] = w;
          }
        }
      }
    }
    __syncthreads(); // S8

    // ---- phase 8: O[r] = O[r]*scale + w*h (registers; LDS broadcast)
    #pragma unroll
    for (int r = 0; r < DRR; ++r) {
      float scl = sh_scale[row][r];
      float w = sh_w[row][r];
      OA[r]  = OA[r]  * scl + w * hnA;
      OBv[r] = OBv[r] * scl + w * hnB;
    }
  }

  // ---- finalize: y_h = out_W . (O/L), bce, predictions, loss reduce
  float pA = 0.f, pB = 0.f;
  #pragma unroll
  for (int r = 0; r < DRR; ++r) {
    float invL = 1.f / sh_L[row][r];
    pA += out_W[r * HD + jA] * (OA[r]  * invL);
    pB += out_W[r * HD + jB] * (OBv[r] * invL);
  }
  float* sred = &sh_gates[0][0];  // 4096 floats of scratch
  __syncthreads();
  sred[row * 256 + jA] = pA;
  sred[row * 256 + jB] = pB;
  __syncthreads();
  if (tid < 4) {
    float acc = 0.f;
    for (int k = 0; k < 256; ++k) acc += sred[tid * 256 + k];
    float yh = acc + out_b[0];
    int b = b0 + tid;
    float lab = labels[b], tr = is_train[b];
    float bce = fmaxf(yh, 0.f) - yh * lab + log1pf(expf(-fabsf(yh)));
    atomicAdd(&ws[1], bce * tr);
    out[1 + b] = 1.f / (1.f + expf(-yh));
  }
  __syncthreads();
  sred[tid] = (float)lossAcc;
  __syncthreads();
  for (int off = 256; off > 0; off >>= 1) {
    if (tid < off) sred[tid] += sred[tid + off];
    __syncthreads();
  }
  if (tid == 0) atomicAdd(&ws[0], sred[0]);
}

__global__ void final_kernel(const float* __restrict__ ws, float* __restrict__ out) {
  if (threadIdx.x == 0 && blockIdx.x == 0) {
    out[0] = ws[0] / (float)SS + 0.1f * (ws[1] / (ws[2] + 1e-5f));
  }
}

extern "C" void kernel_launch(void* const* d_in, const int* in_sizes, int n_in,
                              void* d_out, int out_size, void* d_ws, size_t ws_size,
                              hipStream_t stream) {
  const float* values   = (const float*)d_in[0];
  const float* masks    = (const float*)d_in[1];
  const float* deltas   = (const float*)d_in[2];
  const float* labels   = (const float*)d_in[3];
  const float* is_train = (const float*)d_in[4];
  const float* td_h_W   = (const float*)d_in[5];
  const float* td_h_b   = (const float*)d_in[6];
  const float* td_x_W   = (const float*)d_in[7];
  const float* td_x_b   = (const float*)d_in[8];
  const float* hist_W   = (const float*)d_in[9];
  const float* hist_b   = (const float*)d_in[10];
  const float* feat_W   = (const float*)d_in[11];
  const float* feat_b   = (const float*)d_in[12];
  const float* comb_W   = (const float*)d_in[13];
  const float* comb_b   = (const float*)d_in[14];
  const float* W_ih     = (const float*)d_in[15];
  const float* b_ih     = (const float*)d_in[16];
  const float* W_hh     = (const float*)d_in[17];
  const float* b_hh     = (const float*)d_in[18];
  const float* Ws1_W    = (const float*)d_in[19];
  const float* Ws1_b    = (const float*)d_in[20];
  const float* Ws2_W    = (const float*)d_in[21];
  const float* Ws2_b    = (const float*)d_in[22];
  const float* out_W    = (const float*)d_in[23];
  const float* out_b    = (const float*)d_in[24];
  float* out = (float*)d_out;
  float* ws  = (float*)d_ws;

  short* b5 = (short*)((char*)d_ws + WS_B5_OFS);
  short* b6 = (short*)((char*)d_ws + WS_B6_OFS);
  short* b3 = (short*)((char*)d_ws + WS_B3_OFS);
  short* b2 = (short*)((char*)d_ws + WS_B2_OFS);
  short* b7 = (short*)((char*)d_ws + WS_B7_OFS);

  convert_weights<<<(CW_TOTAL + 255) / 256, 256, 0, stream>>>(
      W_ih, W_hh, Ws1_W, hist_W, td_h_W, Ws2_W, b5, b6, b3, b2, b7);
  prep_kernel<<<SS, 256, 0, stream>>>(masks, is_train, ws);
  rits_main<<<BB / 4, 512, 0, stream>>>(
      values, masks, deltas, labels, is_train,
      td_h_b, td_x_W, td_x_b, hist_b, feat_W, feat_b, comb_W, comb_b,
      b_ih, b_hh, Ws1_b, Ws2_W, Ws2_b, out_W, out_b, out, ws);
  final_kernel<<<1, 64, 0, stream>>>(ws, out);
}